// Round 15
// baseline (225.181 us; speedup 1.0000x reference)
//
#include <hip/hip_runtime.h>
#include <math.h>

#define NUM_HEADS 32
#define HEAD_DIM 128
#define NUM_KV_HEADS 8
#define SCALE 0.08838834764831845f
#define EPS 1e-8f
#define MAX_SEG 512
#define QT 32            // q rows per block
#define BLK 512          // 8 waves
#define SEGC_MAX 16      // 512 keys / 32
#define PB_STRIDE 520    // bf16 elems: 1040 B, %16==0, %128==16
#define PD_STRIDE 136    // compact delta P: 272 B/row, %16==0
#define PD_MAX 128       // compact path only when nss <= 128
#define SAL_PAD 576
#define SAL_STRIDE 640   // vdT row stride (zero-padded so chunk reads never hit garbage)
#define TLD 130
#define CD (NUM_HEADS * HEAD_DIM)

typedef __bf16 bf16x8 __attribute__((ext_vector_type(8)));
typedef __bf16 bf16x4 __attribute__((ext_vector_type(4)));
typedef float  f32x4  __attribute__((ext_vector_type(4)));

#define MFMA16(a, b, c) __builtin_amdgcn_mfma_f32_16x16x32_bf16((a), (b), (c), 0, 0, 0)

__device__ __forceinline__ int lower_bound_i(const int* __restrict__ a, int n, int key) {
    int lo = 0, hi = n;
    while (lo < hi) { int mid = (lo + hi) >> 1; if (a[mid] < key) lo = mid + 1; else hi = mid; }
    return lo;
}
__device__ __forceinline__ int bsearch_eq(const int* __restrict__ a, int n, int key) {
    int lo = lower_bound_i(a, n, key);
    return (lo < n && a[lo] == key) ? lo : -1;
}

__device__ __forceinline__ void red16(float& xn, float& xc, float& xd) {
#pragma unroll
    for (int m = 1; m <= 8; m <<= 1) {
        xn += __shfl_xor(xn, m, 64);
        xc += __shfl_xor(xc, m, 64);
        xd += __shfl_xor(xd, m, 64);
    }
}

// ------- mega-prep: conv K+Q | vnewT(+vdScat) fused | vdT compact | tables -------
__global__ void prep(const float* __restrict__ k, const float* __restrict__ q,
                     const float* __restrict__ v,
                     const float* __restrict__ vc, const int* __restrict__ idx,
                     const int* __restrict__ cu,
                     __bf16* __restrict__ kb, __bf16* __restrict__ qb,
                     __bf16* __restrict__ vnewT,
                     __bf16* __restrict__ vdScat, __bf16* __restrict__ vdT,
                     int* __restrict__ tinfo, int* __restrict__ rowsal,
                     int T, int Tpad, int n_sal, int n_seq,
                     int nb_conv, int nb_vt, int nb_vd, int use_compact) {
    __shared__ __bf16 tileN[64 * TLD];
    __shared__ __bf16 tileD[64 * TLD];
    __shared__ int sal_of[64];
    const int b = blockIdx.x;
    const int tid = threadIdx.x;

    if (b < nb_conv) {
        // fp32 K -> bf16 kb, then fp32 Q -> bf16 qb (one bf16x8 per thread)
        const int n8k = T * NUM_KV_HEADS * HEAD_DIM / 8;
        const int n8q = T * NUM_HEADS * HEAD_DIM / 8;
        const int i = b * 256 + tid;
        if (i < n8k) {
            const float4* s4 = (const float4*)(k + (size_t)i * 8);
            float4 a = s4[0], bb = s4[1];
            bf16x8 o;
            o[0]=(__bf16)a.x; o[1]=(__bf16)a.y; o[2]=(__bf16)a.z; o[3]=(__bf16)a.w;
            o[4]=(__bf16)bb.x; o[5]=(__bf16)bb.y; o[6]=(__bf16)bb.z; o[7]=(__bf16)bb.w;
            *(bf16x8*)(kb + (size_t)i * 8) = o;
        } else if (i < n8k + n8q) {
            const int j = i - n8k;
            const float4* s4 = (const float4*)(q + (size_t)j * 8);
            float4 a = s4[0], bb = s4[1];
            bf16x8 o;
            o[0]=(__bf16)a.x; o[1]=(__bf16)a.y; o[2]=(__bf16)a.z; o[3]=(__bf16)a.w;
            o[4]=(__bf16)bb.x; o[5]=(__bf16)bb.y; o[6]=(__bf16)bb.z; o[7]=(__bf16)bb.w;
            *(bf16x8*)(qb + (size_t)j * 8) = o;
        }
        return;
    }
    if (b < nb_conv + nb_vt * NUM_KV_HEADS) {
        // fused: vnewT[kv][d][row]; vdScat only needed for the dense fallback
        const int bb = b - nb_conv;
        const int kv = bb / nb_vt;
        const int r0 = (bb % nb_vt) * 64;
        if (tid < 64) sal_of[tid] = bsearch_eq(idx, n_sal, r0 + tid);
        __syncthreads();
        for (int ii = tid; ii < 64 * 32; ii += 256) {
            int r = ii >> 5, c4 = ii & 31;
            int row = r0 + r;
            float4 fN = {0.f, 0.f, 0.f, 0.f};
            float4 fD = {0.f, 0.f, 0.f, 0.f};
            if (row < T) {
                int s2 = sal_of[r];
                if (s2 >= 0) {
                    float4 a  = *(const float4*)(v  + ((size_t)s2  * NUM_KV_HEADS + kv) * HEAD_DIM + c4 * 4);
                    float4 c  = *(const float4*)(vc + ((size_t)row * NUM_KV_HEADS + kv) * HEAD_DIM + c4 * 4);
                    fN = a;
                    if (!use_compact) {
                        fD.x = a.x - c.x; fD.y = a.y - c.y; fD.z = a.z - c.z; fD.w = a.w - c.w;
                    }
                } else {
                    fN = *(const float4*)(vc + ((size_t)row * NUM_KV_HEADS + kv) * HEAD_DIM + c4 * 4);
                }
            }
            __bf16* tn = &tileN[r * TLD + c4 * 4];
            tn[0] = (__bf16)fN.x; tn[1] = (__bf16)fN.y; tn[2] = (__bf16)fN.z; tn[3] = (__bf16)fN.w;
            if (!use_compact) {
                __bf16* td = &tileD[r * TLD + c4 * 4];
                td[0] = (__bf16)fD.x; td[1] = (__bf16)fD.y; td[2] = (__bf16)fD.z; td[3] = (__bf16)fD.w;
            }
        }
        __syncthreads();
        for (int ii = tid; ii < 128 * 8; ii += 256) {
            int d = ii >> 3, rg = ii & 7;
            int row_out = r0 + rg * 8;
            if (row_out < Tpad) {
                bf16x8 oN;
#pragma unroll
                for (int j = 0; j < 8; j++) oN[j] = tileN[(rg * 8 + j) * TLD + d];
                *(bf16x8*)(vnewT + ((size_t)kv * HEAD_DIM + d) * Tpad + row_out) = oN;
                if (!use_compact) {
                    bf16x8 oD;
#pragma unroll
                    for (int j = 0; j < 8; j++) oD[j] = tileD[(rg * 8 + j) * TLD + d];
                    *(bf16x8*)(vdScat + ((size_t)kv * HEAD_DIM + d) * Tpad + row_out) = oD;
                }
            }
        }
        return;
    }
    if (b < nb_conv + nb_vt * NUM_KV_HEADS + nb_vd * NUM_KV_HEADS) {
        // compact vdT[kv][d][s] (zero-padded to SAL_STRIDE)
        const int bb = b - nb_conv - nb_vt * NUM_KV_HEADS;
        const int kv = bb / nb_vd;
        const int s0 = (bb % nb_vd) * 64;
        for (int ii = tid; ii < 64 * 32; ii += 256) {
            int r = ii >> 5, c4 = ii & 31;
            int s = s0 + r;
            float4 f = {0.f, 0.f, 0.f, 0.f};
            if (s < n_sal) {
                int row = idx[s];
                float4 a  = *(const float4*)(v  + ((size_t)s   * NUM_KV_HEADS + kv) * HEAD_DIM + c4 * 4);
                float4 c2 = *(const float4*)(vc + ((size_t)row * NUM_KV_HEADS + kv) * HEAD_DIM + c4 * 4);
                f.x = a.x - c2.x; f.y = a.y - c2.y; f.z = a.z - c2.z; f.w = a.w - c2.w;
            }
            __bf16* tp = &tileN[r * TLD + c4 * 4];
            tp[0] = (__bf16)f.x; tp[1] = (__bf16)f.y; tp[2] = (__bf16)f.z; tp[3] = (__bf16)f.w;
        }
        __syncthreads();
        for (int ii = tid; ii < 128 * 8; ii += 256) {
            int d = ii >> 3, rg = ii & 7;
            bf16x8 o;
#pragma unroll
            for (int j = 0; j < 8; j++) o[j] = tileN[(rg * 8 + j) * TLD + d];
            *(bf16x8*)(vdT + ((size_t)kv * HEAD_DIM + d) * SAL_STRIDE + s0 + rg * 8) = o;
        }
        return;
    }
    // final block: rowsal table + per-tile segment info (incl. salient range)
    {
        for (int i = tid; i < T; i += 256) rowsal[i] = -1;
        __syncthreads();
        for (int s = tid; s < n_sal; s += 256) rowsal[idx[s]] = s;
        const int NT = T / QT;
        for (int t = tid; t < NT; t += 256) {
            const int r0 = t * QT;
            int a = 0, e = T;
            for (int s = 0; s < n_seq; s++) {
                int x = cu[s], y = cu[s + 1];
                if (r0 >= x && r0 < y) { a = x; e = y; }
            }
            tinfo[t * 4 + 0] = a;
            tinfo[t * 4 + 1] = e;
            tinfo[t * 4 + 2] = lower_bound_i(idx, n_sal, a);
            tinfo[t * 4 + 3] = lower_bound_i(idx, n_sal, e);
        }
    }
}

// ---------------- main fused attention ----------------

// fallback tile for partial segments (not hit in the bench shape)
#define QK_TILE_GEN(ttc) {                                                                  \
    const int t_ = wave * 4 + (ttc);                                                        \
    if (t_ < ntiles) {                                                                      \
        int key_ = seg_start + t_ * 16 + lm;                                                \
        if (key_ >= seg_end) key_ = seg_end - 1;                                            \
        const __bf16* kp_ = kb + ((size_t)key_ * NUM_KV_HEADS + kvh) * HEAD_DIM + quad * 8; \
        const bf16x8 bk0_ = *(const bf16x8*)(kp_);                                          \
        const bf16x8 bk1_ = *(const bf16x8*)(kp_ + 32);                                     \
        const bf16x8 bk2_ = *(const bf16x8*)(kp_ + 64);                                     \
        const bf16x8 bk3_ = *(const bf16x8*)(kp_ + 96);                                     \
        f32x4 a0_ = {0.f,0.f,0.f,0.f}, a1_ = {0.f,0.f,0.f,0.f};                             \
        a0_ = MFMA16(bk0_, aq00, a0_);  a1_ = MFMA16(bk0_, aq10, a1_);                      \
        a0_ = MFMA16(bk1_, aq01, a0_);  a1_ = MFMA16(bk1_, aq11, a1_);                      \
        a0_ = MFMA16(bk2_, aq02, a0_);  a1_ = MFMA16(bk2_, aq12, a1_);                      \
        a0_ = MFMA16(bk3_, aq03, a0_);  a1_ = MFMA16(bk3_, aq13, a1_);                      \
        bf16x4 pk0_, pk1_;                                                                  \
        _Pragma("unroll")                                                                   \
        for (int r_ = 0; r_ < 4; r_++) {                                                    \
            const int kl_ = t_ * 16 + quad * 4 + r_;                                        \
            const bool ok_ = (kl_ < seg_len);                                               \
            float e0_ = ok_ ? __expf(a0_[r_] * SCALE) : 0.f;                                \
            float e1_ = ok_ ? __expf(a1_[r_] * SCALE) : 0.f;                                \
            ps0 += e0_; ps1 += e1_;                                                         \
            pk0_[r_] = (__bf16)e0_; pk1_[r_] = (__bf16)e1_;                                 \
            if (compact && ok_) {                                                           \
                int sr_ = rowsal[seg_start + kl_];                                          \
                if (sr_ >= 0) {                                                             \
                    int c_ = sr_ - s_lo;                                                    \
                    Pd[lm * PD_STRIDE + c_]        = pk0_[r_];                              \
                    Pd[(16 + lm) * PD_STRIDE + c_] = pk1_[r_];                              \
                }                                                                           \
            }                                                                               \
        }                                                                                   \
        *(bf16x4*)&Pb[lm * PB_STRIDE + t_ * 16 + quad * 4] = pk0_;                          \
        *(bf16x4*)&Pb[(16 + lm) * PB_STRIDE + t_ * 16 + quad * 4] = pk1_;                   \
    } }

#define LOADK(buf, t) {                                                                     \
    const __bf16* kn_ = kp + (size_t)(t) * 16 * krow;                                       \
    kk[buf][0] = *(const bf16x8*)(kn_);                                                     \
    kk[buf][1] = *(const bf16x8*)(kn_ + 32);                                                \
    kk[buf][2] = *(const bf16x8*)(kn_ + 64);                                                \
    kk[buf][3] = *(const bf16x8*)(kn_ + 96); }

__global__ __launch_bounds__(BLK, 4)
void attn_mfma(const __bf16* __restrict__ qb, const __bf16* __restrict__ kb,
               const __bf16* __restrict__ vnewT, const __bf16* __restrict__ vdScat,
               const __bf16* __restrict__ vdT,
               const float* __restrict__ c_cache, const int* __restrict__ tinfo,
               const int* __restrict__ rowsal,
               float* __restrict__ out_c, float* __restrict__ cospart,
               int Tpad, int use_compact) {
    // XCD pin: bid&7 -> kvh, so each XCD's L2 holds one kv-head's K/V slabs
    const int bid  = blockIdx.x;
    const int kvh  = bid & 7;
    const int rem  = bid >> 3;
    const int h    = kvh * 4 + (rem & 3);
    const int qt   = rem >> 2;
    const int qrow0 = qt * QT;
    const int tid   = threadIdx.x;
    const int wave  = tid >> 6;
    const int lane  = tid & 63;
    const int lm    = lane & 15;
    const int quad  = lane >> 4;

    __shared__ __align__(16) __bf16 Pb[QT * PB_STRIDE];   // exp(scores), dense
    __shared__ __align__(16) __bf16 Pd[QT * PD_STRIDE];   // exp(scores), salient-compact
    __shared__ float wred[8 * QT];
    __shared__ float linv[QT];
    __shared__ int   salrow[QT];
    __shared__ float cp[8 * 3 * QT];

    const int4 ti = *(const int4*)(tinfo + qt * 4);
    const int seg_start = ti.x, seg_end = ti.y, s_lo = ti.z, s_hi = ti.w;
    const int seg_len = seg_end - seg_start;
    const int nss    = s_hi - s_lo;
    const int ntiles = (seg_len + 15) >> 4;
    const int SEGC   = (seg_len + 31) >> 5;
    const int dim = wave * 16 + lm;
    const bool compact = use_compact && (nss <= PD_MAX);   // block-uniform
    const bool fullseg = (seg_len == MAX_SEG);

    if (tid < QT) salrow[tid] = rowsal[qrow0 + tid];
    if (ntiles * 16 < SEGC * 32) {   // zero Pb tail half-chunk
        for (int ii = tid; ii < QT * 16; ii += BLK) {
            int row = ii >> 4, col = ntiles * 16 + (ii & 15);
            Pb[row * PB_STRIDE + col] = (__bf16)0.f;
        }
    }
    if (compact) {                   // zero Pd (columns >= nss must be 0)
        const bf16x8 z = {0,0,0,0,0,0,0,0};
        for (int ii = tid; ii < QT * PD_STRIDE / 8; ii += BLK)
            ((bf16x8*)Pd)[ii] = z;
    }

    // Q B-fragments: direct bf16 loads (pre-converted in prep) — 8 x 16B, no cvt
    bf16x8 aq00, aq01, aq02, aq03, aq10, aq11, aq12, aq13;
    {
        const __bf16* qp0 = qb + ((size_t)(qrow0 + lm) * NUM_HEADS + h) * HEAD_DIM + quad * 8;
        const __bf16* qp1 = qb + ((size_t)(qrow0 + 16 + lm) * NUM_HEADS + h) * HEAD_DIM + quad * 8;
        aq00 = *(const bf16x8*)(qp0);      aq01 = *(const bf16x8*)(qp0 + 32);
        aq02 = *(const bf16x8*)(qp0 + 64); aq03 = *(const bf16x8*)(qp0 + 96);
        aq10 = *(const bf16x8*)(qp1);      aq11 = *(const bf16x8*)(qp1 + 32);
        aq12 = *(const bf16x8*)(qp1 + 64); aq13 = *(const bf16x8*)(qp1 + 96);
    }

    // epilogue operands issued early: overlap with QK
    const float* cbase = c_cache + (size_t)qrow0 * CD + h * HEAD_DIM + dim;
    float cold[2][4];
#pragma unroll
    for (int rt = 0; rt < 2; rt++)
#pragma unroll
        for (int r = 0; r < 4; r++)
            cold[rt][r] = cbase[(size_t)(rt * 16 + quad * 4 + r) * CD];

    // ---- QK^T (A=K, B=Q), prefetch distance 2; dual-write salient P into Pd ----
    float ps0 = 0.f, ps1 = 0.f;
    if (fullseg) {
        const size_t krow = (size_t)NUM_KV_HEADS * HEAD_DIM;
        const __bf16* kp = kb + (size_t)(seg_start + wave * 64 + lm) * krow
                              + (size_t)kvh * HEAD_DIM + quad * 8;
        bf16x8 kk[3][4];
        LOADK(0, 0)
        LOADK(1, 1)
#pragma unroll
        for (int tt = 0; tt < 4; tt++) {
            if (tt + 2 < 4) LOADK((tt + 2) % 3, tt + 2)
            const int cur = tt % 3;
            f32x4 a0_ = {0.f,0.f,0.f,0.f}, a1_ = {0.f,0.f,0.f,0.f};
            a0_ = MFMA16(kk[cur][0], aq00, a0_);  a1_ = MFMA16(kk[cur][0], aq10, a1_);
            a0_ = MFMA16(kk[cur][1], aq01, a0_);  a1_ = MFMA16(kk[cur][1], aq11, a1_);
            a0_ = MFMA16(kk[cur][2], aq02, a0_);  a1_ = MFMA16(kk[cur][2], aq12, a1_);
            a0_ = MFMA16(kk[cur][3], aq03, a0_);  a1_ = MFMA16(kk[cur][3], aq13, a1_);
            const int t_ = wave * 4 + tt;
            bf16x4 pk0_, pk1_;
#pragma unroll
            for (int r_ = 0; r_ < 4; r_++) {
                float e0_ = __expf(a0_[r_] * SCALE);
                float e1_ = __expf(a1_[r_] * SCALE);
                ps0 += e0_; ps1 += e1_;
                pk0_[r_] = (__bf16)e0_; pk1_[r_] = (__bf16)e1_;
            }
            *(bf16x4*)&Pb[lm * PB_STRIDE + t_ * 16 + quad * 4] = pk0_;
            *(bf16x4*)&Pb[(16 + lm) * PB_STRIDE + t_ * 16 + quad * 4] = pk1_;
            if (compact) {
                const int4 sal4 = *(const int4*)&rowsal[seg_start + t_ * 16 + quad * 4];
                const int srl[4] = {sal4.x, sal4.y, sal4.z, sal4.w};
#pragma unroll
                for (int r_ = 0; r_ < 4; r_++) {
                    if (srl[r_] >= 0) {
                        const int c_ = srl[r_] - s_lo;
                        Pd[lm * PD_STRIDE + c_]        = pk0_[r_];
                        Pd[(16 + lm) * PD_STRIDE + c_] = pk1_[r_];
                    }
                }
            }
        }
    } else {
        QK_TILE_GEN(0) QK_TILE_GEN(1) QK_TILE_GEN(2) QK_TILE_GEN(3)
    }
#pragma unroll
    for (int m = 16; m <= 32; m <<= 1) {
        ps0 += __shfl_xor(ps0, m, 64);
        ps1 += __shfl_xor(ps1, m, 64);
    }
    if (quad == 0) {
        wred[wave * QT + lm]      = ps0;
        wred[wave * QT + 16 + lm] = ps1;
    }

    // PV pointers
    const __bf16* vF = vnewT  + ((size_t)kvh * HEAD_DIM + dim) * Tpad + seg_start + quad * 8;
    const __bf16* vD = vdScat + ((size_t)kvh * HEAD_DIM + dim) * Tpad + seg_start + quad * 8;
    const __bf16* pb0 = &Pb[lm * PB_STRIDE + quad * 8];
    const __bf16* pb1 = &Pb[(16 + lm) * PB_STRIDE + quad * 8];

    f32x4 accF0 = {0.f,0.f,0.f,0.f}, accF1 = {0.f,0.f,0.f,0.f};
    f32x4 accD0 = {0.f,0.f,0.f,0.f}, accD1 = {0.f,0.f,0.f,0.f};
    bf16x8 fv[4], dv[4];

    if (compact) {
        // pre-barrier self-chunk PV: this wave's Pb columns (wave*64..+64) were
        // written by THIS wave (same-wave LDS ops are in-order) — start PV on them
        // while other waves finish QK.
        if (fullseg) {
            const int c0 = wave * 2;
            const bf16x8 f0_ = *(const bf16x8*)(vF + c0 * 32);
            const bf16x8 f1_ = *(const bf16x8*)(vF + c0 * 32 + 32);
            accF0 = MFMA16(*(const bf16x8*)(pb0 + c0 * 32), f0_, accF0);
            accF1 = MFMA16(*(const bf16x8*)(pb1 + c0 * 32), f0_, accF1);
            accF0 = MFMA16(*(const bf16x8*)(pb0 + c0 * 32 + 32), f1_, accF0);
            accF1 = MFMA16(*(const bf16x8*)(pb1 + c0 * 32 + 32), f1_, accF1);
        }
    } else {
        // dense fallback keeps the 3-deep prefetch machinery
#pragma unroll
        for (int i = 0; i < 3; i++) {
            fv[i] = *(const bf16x8*)(vF + i * 32);
            dv[i] = *(const bf16x8*)(vD + i * 32);
        }
    }

    __syncthreads();   // barrier1: Pb + Pd + wred complete
    if (tid < QT) {
        float s = 0.f;
#pragma unroll
        for (int w = 0; w < 8; w++) s += wred[w * QT + tid];
        linv[tid] = 1.f / s;
    }

    __builtin_amdgcn_s_setprio(1);
    if (compact) {
        // ---- compact PV-delta: <=4 chunks over vdT + Pd ----
        const int ndc = (nss + 31) >> 5;
        const __bf16* vdb = vdT + ((size_t)kvh * HEAD_DIM + dim) * SAL_STRIDE + s_lo + quad * 8;
        const bool al8 = ((s_lo & 7) == 0);
        for (int dc = 0; dc < ndc; dc++) {
            bf16x8 bvD;
            const __bf16* vp = vdb + dc * 32;
            if (al8) bvD = *(const bf16x8*)vp;
            else {
#pragma unroll
                for (int j = 0; j < 8; j++) bvD[j] = vp[j];
            }
            const bf16x8 aD0 = *(const bf16x8*)&Pd[lm * PD_STRIDE + dc * 32 + quad * 8];
            const bf16x8 aD1 = *(const bf16x8*)&Pd[(16 + lm) * PD_STRIDE + dc * 32 + quad * 8];
            accD0 = MFMA16(aD0, bvD, accD0);
            accD1 = MFMA16(aD1, bvD, accD1);
        }
        // ---- PV-full: plain unrolled loop (compiler schedules loads); skip self chunks ----
        if (fullseg) {
#pragma unroll
            for (int cc = 0; cc < SEGC_MAX; cc++) {
                if ((cc >> 1) == wave) continue;   // done pre-barrier
                const bf16x8 bF_ = *(const bf16x8*)(vF + cc * 32);
                accF0 = MFMA16(*(const bf16x8*)(pb0 + cc * 32), bF_, accF0);
                accF1 = MFMA16(*(const bf16x8*)(pb1 + cc * 32), bF_, accF1);
            }
        } else {
            for (int cc = 0; cc < SEGC; cc++) {
                const bf16x8 bF_ = *(const bf16x8*)(vF + cc * 32);
                accF0 = MFMA16(*(const bf16x8*)(pb0 + cc * 32), bF_, accF0);
                accF1 = MFMA16(*(const bf16x8*)(pb1 + cc * 32), bF_, accF1);
            }
        }
    } else {
        // ---- dense fallback: fused PV over vnewT + vdScat (R7 path, verbatim) ----
        if (SEGC == SEGC_MAX) {
            bf16x8 a0c = *(const bf16x8*)(pb0);
            bf16x8 a1c = *(const bf16x8*)(pb1);
#pragma unroll
            for (int cc = 0; cc < SEGC_MAX; cc++) {
                bf16x8 a0n, a1n;
                if (cc + 1 < SEGC_MAX) {
                    a0n = *(const bf16x8*)(pb0 + (cc + 1) * 32);
                    a1n = *(const bf16x8*)(pb1 + (cc + 1) * 32);
                }
                if (cc + 3 < SEGC_MAX) {
                    fv[(cc + 3) & 3] = *(const bf16x8*)(vF + (cc + 3) * 32);
                    dv[(cc + 3) & 3] = *(const bf16x8*)(vD + (cc + 3) * 32);
                }
                const int cur = cc & 3;
                accF0 = MFMA16(a0c, fv[cur], accF0);
                accF1 = MFMA16(a1c, fv[cur], accF1);
                accD0 = MFMA16(a0c, dv[cur], accD0);
                accD1 = MFMA16(a1c, dv[cur], accD1);
                if (cc + 1 < SEGC_MAX) { a0c = a0n; a1c = a1n; }
            }
        } else {
            for (int cc = 0; cc < SEGC; cc++) {
                const bf16x8 bF_ = *(const bf16x8*)(vF + cc * 32);
                const bf16x8 bD_ = *(const bf16x8*)(vD + cc * 32);
                const bf16x8 a0_ = *(const bf16x8*)(pb0 + cc * 32);
                const bf16x8 a1_ = *(const bf16x8*)(pb1 + cc * 32);
                accF0 = MFMA16(a0_, bF_, accF0);
                accF1 = MFMA16(a1_, bF_, accF1);
                accD0 = MFMA16(a0_, bD_, accD0);
                accD1 = MFMA16(a1_, bD_, accD1);
            }
        }
    }
    __builtin_amdgcn_s_setprio(0);
    __syncthreads();   // barrier2: linv visible

    // ---- epilogue: outputs + cosine partials, single pass over all 32 rows ----
    float* obase = out_c + (size_t)qrow0 * CD + h * HEAD_DIM + dim;
#pragma unroll
    for (int rt = 0; rt < 2; rt++) {
#pragma unroll
        for (int r = 0; r < 4; r++) {
            const int row = rt * 16 + quad * 4 + r;
            const float c_old = cold[rt][r];
            const float li = linv[row];
            const float aF = (rt == 0) ? accF0[r] : accF1[r];
            const float aD = (rt == 0) ? accD0[r] : accD1[r];
            const float o = (salrow[row] >= 0) ? aF * li : c_old + aD * li;
            obase[(size_t)row * CD] = o;
            float xn = o * c_old, xc = c_old * c_old, xd = o * o;
            red16(xn, xc, xd);
            if (lm == 0) {
                cp[(wave * 3 + 0) * QT + row] = xn;
                cp[(wave * 3 + 1) * QT + row] = xc;
                cp[(wave * 3 + 2) * QT + row] = xd;
            }
        }
    }
    __syncthreads();   // barrier3: cp complete
    for (int ii = tid; ii < 3 * QT; ii += BLK) {
        int c = ii >> 5, row = ii & 31;
        float s = 0.f;
#pragma unroll
        for (int w = 0; w < 8; w++) s += cp[(w * 3 + c) * QT + row];
        // layout [row][3][32] for coalesced finalize
        cospart[((size_t)(qrow0 + row) * 3 + c) * NUM_HEADS + h] = s;
    }
}

// ---------------- cos finalize: one row per wave, coalesced ----------------
__global__ void cos_finalize(const float* __restrict__ cospart, float* __restrict__ out_cos, int T) {
    const int lane = threadIdx.x & 63;
    const int row  = blockIdx.x * 4 + (threadIdx.x >> 6);
    if (row >= T) return;
    const float* p = cospart + (size_t)row * (NUM_HEADS * 3);
    float a = p[lane];                               // lanes 0-31: num, lanes 32-63: den_c
    float b = (lane < 32) ? p[64 + lane] : 0.f;      // den_n
#pragma unroll
    for (int m = 1; m <= 16; m <<= 1) {
        a += __shfl_xor(a, m, 64);
        b += __shfl_xor(b, m, 64);
    }
    float den_c = __shfl(a, 32, 64);
    if (lane == 0) out_cos[row] = a / (sqrtf(den_c) * sqrtf(b) + EPS);
}

extern "C" void kernel_launch(void* const* d_in, const int* in_sizes, int n_in,
                              void* d_out, int out_size, void* d_ws, size_t ws_size,
                              hipStream_t stream) {
    const float* q       = (const float*)d_in[0];
    const float* k       = (const float*)d_in[1];
    const float* v       = (const float*)d_in[2];
    const float* v_cache = (const float*)d_in[3];
    const float* c_cache = (const float*)d_in[4];
    const int*   idx     = (const int*)d_in[5];
    const int*   cu      = (const int*)d_in[6];

    const int T     = in_sizes[0] / CD;
    const int n_sal = in_sizes[5];
    const int n_seq = in_sizes[6] - 1;
    const int Tpad  = T + 32;
    const int NT    = T / QT;
    const int use_compact = (n_sal <= SAL_PAD) ? 1 : 0;

    float* out_c   = (float*)d_out;
    float* out_cos = out_c + (size_t)T * CD;

    char* wsp = (char*)d_ws;
    size_t off = 0;
    __bf16* kb = (__bf16*)(wsp + off);
    off += (((size_t)T * NUM_KV_HEADS * HEAD_DIM * 2) + 255) & ~(size_t)255;
    __bf16* qb = (__bf16*)(wsp + off);
    off += (((size_t)T * NUM_HEADS * HEAD_DIM * 2) + 255) & ~(size_t)255;
    __bf16* vnewT = (__bf16*)(wsp + off);
    off += (((size_t)NUM_KV_HEADS * HEAD_DIM * Tpad * 2) + 255) & ~(size_t)255;
    __bf16* vdScat = (__bf16*)(wsp + off);
    off += (((size_t)NUM_KV_HEADS * HEAD_DIM * Tpad * 2) + 255) & ~(size_t)255;
    __bf16* vdT = (__bf16*)(wsp + off);
    off += (((size_t)NUM_KV_HEADS * HEAD_DIM * SAL_STRIDE * 2) + 255) & ~(size_t)255;
    float* cospart = (float*)(wsp + off);
    off += ((size_t)T * NUM_HEADS * 3 * 4 + 255) & ~(size_t)255;
    int* tinfo = (int*)(wsp + off);
    off += ((size_t)NT * 4 * 4 + 255) & ~(size_t)255;
    int* rowsal = (int*)(wsp + off);
    off += ((size_t)T * 4 + 255) & ~(size_t)255;
    (void)ws_size;

    const int n8_tot  = T * HEAD_DIM * (NUM_KV_HEADS + NUM_HEADS) / 8;
    const int nb_conv = (n8_tot + 255) / 256;
    const int nb_vt   = (Tpad + 63) / 64;
    const int nb_vd   = use_compact ? (SAL_STRIDE / 64) : 0;
    const int nb_tot  = nb_conv + nb_vt * NUM_KV_HEADS + nb_vd * NUM_KV_HEADS + 1;

    prep<<<nb_tot, 256, 0, stream>>>(k, q, v, v_cache, idx, cu, kb, qb, vnewT,
                                     vdScat, vdT, tinfo, rowsal, T, Tpad, n_sal,
                                     n_seq, nb_conv, nb_vt, nb_vd, use_compact);

    // 1-D grid: bid&7 = kvh (XCD pin), then head-within-group, then q-tile
    attn_mfma<<<NT * NUM_HEADS, BLK, 0, stream>>>(qb, kb, vnewT, vdScat, vdT, c_cache,
                                                  tinfo, rowsal, out_c, cospart,
                                                  Tpad, use_compact);

    cos_finalize<<<(T + 3) / 4, 256, 0, stream>>>(cospart, out_cos, T);
}

// Round 16
// 219.129 us; speedup vs baseline: 1.0276x; 1.0276x over previous
//
#include <hip/hip_runtime.h>
#include <math.h>

#define NUM_HEADS 32
#define HEAD_DIM 128
#define NUM_KV_HEADS 8
#define SCALE 0.08838834764831845f
#define EPS 1e-8f
#define MAX_SEG 512
#define QT 32            // q rows per block
#define BLK 512          // 8 waves
#define SEGC_MAX 16      // 512 keys / 32
#define PB_STRIDE 520    // bf16 elems: 1040 B, %16==0, %128==16
#define PD_STRIDE 136    // compact delta P: 272 B/row, %16==0
#define PD_MAX 128       // compact path only when nss <= 128
#define SAL_PAD 576
#define SAL_STRIDE 640   // vdT row stride (zero-padded so chunk reads never hit garbage)
#define TLD 130
#define CD (NUM_HEADS * HEAD_DIM)

typedef __bf16 bf16x8 __attribute__((ext_vector_type(8)));
typedef __bf16 bf16x4 __attribute__((ext_vector_type(4)));
typedef float  f32x4  __attribute__((ext_vector_type(4)));

#define MFMA16(a, b, c) __builtin_amdgcn_mfma_f32_16x16x32_bf16((a), (b), (c), 0, 0, 0)

__device__ __forceinline__ int lower_bound_i(const int* __restrict__ a, int n, int key) {
    int lo = 0, hi = n;
    while (lo < hi) { int mid = (lo + hi) >> 1; if (a[mid] < key) lo = mid + 1; else hi = mid; }
    return lo;
}
__device__ __forceinline__ int bsearch_eq(const int* __restrict__ a, int n, int key) {
    int lo = lower_bound_i(a, n, key);
    return (lo < n && a[lo] == key) ? lo : -1;
}

__device__ __forceinline__ void red16(float& xn, float& xc, float& xd) {
#pragma unroll
    for (int m = 1; m <= 8; m <<= 1) {
        xn += __shfl_xor(xn, m, 64);
        xc += __shfl_xor(xc, m, 64);
        xd += __shfl_xor(xd, m, 64);
    }
}

// ------- mega-prep: conv K+Q | vnewT(+vdScat) fused | vdT compact | tables -------
__global__ void prep(const float* __restrict__ k, const float* __restrict__ q,
                     const float* __restrict__ v,
                     const float* __restrict__ vc, const int* __restrict__ idx,
                     const int* __restrict__ cu,
                     __bf16* __restrict__ kb, __bf16* __restrict__ qb,
                     __bf16* __restrict__ vnewT,
                     __bf16* __restrict__ vdScat, __bf16* __restrict__ vdT,
                     int* __restrict__ tinfo, int* __restrict__ rowsal,
                     int T, int Tpad, int n_sal, int n_seq,
                     int nb_conv, int nb_vt, int nb_vd, int use_compact) {
    __shared__ __bf16 tileN[64 * TLD];
    __shared__ __bf16 tileD[64 * TLD];
    __shared__ int sal_of[64];
    const int b = blockIdx.x;
    const int tid = threadIdx.x;

    if (b < nb_conv) {
        // fp32 K -> bf16 kb, then fp32 Q -> bf16 qb (one bf16x8 per thread)
        const int n8k = T * NUM_KV_HEADS * HEAD_DIM / 8;
        const int n8q = T * NUM_HEADS * HEAD_DIM / 8;
        const int i = b * 256 + tid;
        if (i < n8k) {
            const float4* s4 = (const float4*)(k + (size_t)i * 8);
            float4 a = s4[0], bb = s4[1];
            bf16x8 o;
            o[0]=(__bf16)a.x; o[1]=(__bf16)a.y; o[2]=(__bf16)a.z; o[3]=(__bf16)a.w;
            o[4]=(__bf16)bb.x; o[5]=(__bf16)bb.y; o[6]=(__bf16)bb.z; o[7]=(__bf16)bb.w;
            *(bf16x8*)(kb + (size_t)i * 8) = o;
        } else if (i < n8k + n8q) {
            const int j = i - n8k;
            const float4* s4 = (const float4*)(q + (size_t)j * 8);
            float4 a = s4[0], bb = s4[1];
            bf16x8 o;
            o[0]=(__bf16)a.x; o[1]=(__bf16)a.y; o[2]=(__bf16)a.z; o[3]=(__bf16)a.w;
            o[4]=(__bf16)bb.x; o[5]=(__bf16)bb.y; o[6]=(__bf16)bb.z; o[7]=(__bf16)bb.w;
            *(bf16x8*)(qb + (size_t)j * 8) = o;
        }
        return;
    }
    if (b < nb_conv + nb_vt * NUM_KV_HEADS) {
        // fused: vnewT[kv][d][row] (+ vdScat when dense fallback needed)
        const int bb = b - nb_conv;
        const int kv = bb / nb_vt;
        const int r0 = (bb % nb_vt) * 64;
        if (tid < 64) sal_of[tid] = bsearch_eq(idx, n_sal, r0 + tid);
        __syncthreads();
        for (int ii = tid; ii < 64 * 32; ii += 256) {
            int r = ii >> 5, c4 = ii & 31;
            int row = r0 + r;
            float4 fN = {0.f, 0.f, 0.f, 0.f};
            float4 fD = {0.f, 0.f, 0.f, 0.f};
            if (row < T) {
                int s2 = sal_of[r];
                if (s2 >= 0) {
                    float4 a  = *(const float4*)(v  + ((size_t)s2  * NUM_KV_HEADS + kv) * HEAD_DIM + c4 * 4);
                    float4 c  = *(const float4*)(vc + ((size_t)row * NUM_KV_HEADS + kv) * HEAD_DIM + c4 * 4);
                    fN = a;
                    fD.x = a.x - c.x; fD.y = a.y - c.y; fD.z = a.z - c.z; fD.w = a.w - c.w;
                } else {
                    fN = *(const float4*)(vc + ((size_t)row * NUM_KV_HEADS + kv) * HEAD_DIM + c4 * 4);
                }
            }
            __bf16* tn = &tileN[r * TLD + c4 * 4];
            tn[0] = (__bf16)fN.x; tn[1] = (__bf16)fN.y; tn[2] = (__bf16)fN.z; tn[3] = (__bf16)fN.w;
            __bf16* td = &tileD[r * TLD + c4 * 4];
            td[0] = (__bf16)fD.x; td[1] = (__bf16)fD.y; td[2] = (__bf16)fD.z; td[3] = (__bf16)fD.w;
        }
        __syncthreads();
        for (int ii = tid; ii < 128 * 8; ii += 256) {
            int d = ii >> 3, rg = ii & 7;
            int row_out = r0 + rg * 8;
            if (row_out < Tpad) {
                bf16x8 oN, oD;
#pragma unroll
                for (int j = 0; j < 8; j++) {
                    oN[j] = tileN[(rg * 8 + j) * TLD + d];
                    oD[j] = tileD[(rg * 8 + j) * TLD + d];
                }
                *(bf16x8*)(vnewT + ((size_t)kv * HEAD_DIM + d) * Tpad + row_out) = oN;
                if (!use_compact)
                    *(bf16x8*)(vdScat + ((size_t)kv * HEAD_DIM + d) * Tpad + row_out) = oD;
            }
        }
        return;
    }
    if (b < nb_conv + nb_vt * NUM_KV_HEADS + nb_vd * NUM_KV_HEADS) {
        // compact vdT[kv][d][s] (zero-padded to SAL_STRIDE)
        const int bb = b - nb_conv - nb_vt * NUM_KV_HEADS;
        const int kv = bb / nb_vd;
        const int s0 = (bb % nb_vd) * 64;
        for (int ii = tid; ii < 64 * 32; ii += 256) {
            int r = ii >> 5, c4 = ii & 31;
            int s = s0 + r;
            float4 f = {0.f, 0.f, 0.f, 0.f};
            if (s < n_sal) {
                int row = idx[s];
                float4 a  = *(const float4*)(v  + ((size_t)s   * NUM_KV_HEADS + kv) * HEAD_DIM + c4 * 4);
                float4 c2 = *(const float4*)(vc + ((size_t)row * NUM_KV_HEADS + kv) * HEAD_DIM + c4 * 4);
                f.x = a.x - c2.x; f.y = a.y - c2.y; f.z = a.z - c2.z; f.w = a.w - c2.w;
            }
            __bf16* tp = &tileN[r * TLD + c4 * 4];
            tp[0] = (__bf16)f.x; tp[1] = (__bf16)f.y; tp[2] = (__bf16)f.z; tp[3] = (__bf16)f.w;
        }
        __syncthreads();
        for (int ii = tid; ii < 128 * 8; ii += 256) {
            int d = ii >> 3, rg = ii & 7;
            bf16x8 o;
#pragma unroll
            for (int j = 0; j < 8; j++) o[j] = tileN[(rg * 8 + j) * TLD + d];
            *(bf16x8*)(vdT + ((size_t)kv * HEAD_DIM + d) * SAL_STRIDE + s0 + rg * 8) = o;
        }
        return;
    }
    // final block: rowsal table + per-tile segment info (incl. salient range)
    {
        for (int i = tid; i < T; i += 256) rowsal[i] = -1;
        __syncthreads();
        for (int s = tid; s < n_sal; s += 256) rowsal[idx[s]] = s;
        const int NT = T / QT;
        for (int t = tid; t < NT; t += 256) {
            const int r0 = t * QT;
            int a = 0, e = T;
            for (int s = 0; s < n_seq; s++) {
                int x = cu[s], y = cu[s + 1];
                if (r0 >= x && r0 < y) { a = x; e = y; }
            }
            tinfo[t * 4 + 0] = a;
            tinfo[t * 4 + 1] = e;
            tinfo[t * 4 + 2] = lower_bound_i(idx, n_sal, a);
            tinfo[t * 4 + 3] = lower_bound_i(idx, n_sal, e);
        }
    }
}

// ---------------- main fused attention ----------------

// fallback tile for partial segments (not hit in the bench shape)
#define QK_TILE_GEN(ttc) {                                                                  \
    const int t_ = wave * 4 + (ttc);                                                        \
    if (t_ < ntiles) {                                                                      \
        int key_ = seg_start + t_ * 16 + lm;                                                \
        if (key_ >= seg_end) key_ = seg_end - 1;                                            \
        const __bf16* kp_ = kb + ((size_t)key_ * NUM_KV_HEADS + kvh) * HEAD_DIM + quad * 8; \
        const bf16x8 bk0_ = *(const bf16x8*)(kp_);                                          \
        const bf16x8 bk1_ = *(const bf16x8*)(kp_ + 32);                                     \
        const bf16x8 bk2_ = *(const bf16x8*)(kp_ + 64);                                     \
        const bf16x8 bk3_ = *(const bf16x8*)(kp_ + 96);                                     \
        f32x4 a0_ = {0.f,0.f,0.f,0.f}, a1_ = {0.f,0.f,0.f,0.f};                             \
        a0_ = MFMA16(bk0_, aq00, a0_);  a1_ = MFMA16(bk0_, aq10, a1_);                      \
        a0_ = MFMA16(bk1_, aq01, a0_);  a1_ = MFMA16(bk1_, aq11, a1_);                      \
        a0_ = MFMA16(bk2_, aq02, a0_);  a1_ = MFMA16(bk2_, aq12, a1_);                      \
        a0_ = MFMA16(bk3_, aq03, a0_);  a1_ = MFMA16(bk3_, aq13, a1_);                      \
        bf16x4 pk0_, pk1_;                                                                  \
        _Pragma("unroll")                                                                   \
        for (int r_ = 0; r_ < 4; r_++) {                                                    \
            const int kl_ = t_ * 16 + quad * 4 + r_;                                        \
            const bool ok_ = (kl_ < seg_len);                                               \
            float e0_ = ok_ ? __expf(a0_[r_] * SCALE) : 0.f;                                \
            float e1_ = ok_ ? __expf(a1_[r_] * SCALE) : 0.f;                                \
            ps0 += e0_; ps1 += e1_;                                                         \
            pk0_[r_] = (__bf16)e0_; pk1_[r_] = (__bf16)e1_;                                 \
            if (compact && ok_) {                                                           \
                int sr_ = rowsal[seg_start + kl_];                                          \
                if (sr_ >= 0) {                                                             \
                    int c_ = sr_ - s_lo;                                                    \
                    Pd[lm * PD_STRIDE + c_]        = pk0_[r_];                              \
                    Pd[(16 + lm) * PD_STRIDE + c_] = pk1_[r_];                              \
                }                                                                           \
            }                                                                               \
        }                                                                                   \
        *(bf16x4*)&Pb[lm * PB_STRIDE + t_ * 16 + quad * 4] = pk0_;                          \
        *(bf16x4*)&Pb[(16 + lm) * PB_STRIDE + t_ * 16 + quad * 4] = pk1_;                   \
    } }

#define LOADK(buf, t) {                                                                     \
    const __bf16* kn_ = kp + (size_t)(t) * 16 * krow;                                       \
    kk[buf][0] = *(const bf16x8*)(kn_);                                                     \
    kk[buf][1] = *(const bf16x8*)(kn_ + 32);                                                \
    kk[buf][2] = *(const bf16x8*)(kn_ + 64);                                                \
    kk[buf][3] = *(const bf16x8*)(kn_ + 96); }

__global__ __launch_bounds__(BLK, 4)
void attn_mfma(const __bf16* __restrict__ qb, const __bf16* __restrict__ kb,
               const __bf16* __restrict__ vnewT, const __bf16* __restrict__ vdScat,
               const __bf16* __restrict__ vdT,
               const float* __restrict__ c_cache, const int* __restrict__ tinfo,
               const int* __restrict__ rowsal,
               float* __restrict__ out_c, float* __restrict__ cospart,
               int Tpad, int use_compact) {
    // XCD pin: bid&7 -> kvh, so each XCD's L2 holds one kv-head's K/V slabs
    const int bid  = blockIdx.x;
    const int kvh  = bid & 7;
    const int rem  = bid >> 3;
    const int h    = kvh * 4 + (rem & 3);
    const int qt   = rem >> 2;
    const int qrow0 = qt * QT;
    const int tid   = threadIdx.x;
    const int wave  = tid >> 6;
    const int lane  = tid & 63;
    const int lm    = lane & 15;
    const int quad  = lane >> 4;

    __shared__ __align__(16) __bf16 Pb[QT * PB_STRIDE];   // exp(scores), dense
    __shared__ __align__(16) __bf16 Pd[QT * PD_STRIDE];   // exp(scores), salient-compact
    __shared__ float wred[8 * QT];
    __shared__ float linv[QT];
    __shared__ int   salrow[QT];
    __shared__ float cp[8 * 3 * QT];

    const int4 ti = *(const int4*)(tinfo + qt * 4);
    const int seg_start = ti.x, seg_end = ti.y, s_lo = ti.z, s_hi = ti.w;
    const int seg_len = seg_end - seg_start;
    const int nss    = s_hi - s_lo;
    const int ntiles = (seg_len + 15) >> 4;
    const int SEGC   = (seg_len + 31) >> 5;
    const int dim = wave * 16 + lm;
    const bool compact = use_compact && (nss <= PD_MAX);   // block-uniform

    if (tid < QT) salrow[tid] = rowsal[qrow0 + tid];
    if (ntiles * 16 < SEGC * 32) {   // zero Pb tail half-chunk
        for (int ii = tid; ii < QT * 16; ii += BLK) {
            int row = ii >> 4, col = ntiles * 16 + (ii & 15);
            Pb[row * PB_STRIDE + col] = (__bf16)0.f;
        }
    }
    if (compact) {                   // zero Pd (columns >= nss must be 0)
        const bf16x8 z = {0,0,0,0,0,0,0,0};
        for (int ii = tid; ii < QT * PD_STRIDE / 8; ii += BLK)
            ((bf16x8*)Pd)[ii] = z;
    }

    // Q B-fragments: direct bf16 loads (pre-converted in prep) — 8 x 16B, no cvt
    bf16x8 aq00, aq01, aq02, aq03, aq10, aq11, aq12, aq13;
    {
        const __bf16* qp0 = qb + ((size_t)(qrow0 + lm) * NUM_HEADS + h) * HEAD_DIM + quad * 8;
        const __bf16* qp1 = qb + ((size_t)(qrow0 + 16 + lm) * NUM_HEADS + h) * HEAD_DIM + quad * 8;
        aq00 = *(const bf16x8*)(qp0);      aq01 = *(const bf16x8*)(qp0 + 32);
        aq02 = *(const bf16x8*)(qp0 + 64); aq03 = *(const bf16x8*)(qp0 + 96);
        aq10 = *(const bf16x8*)(qp1);      aq11 = *(const bf16x8*)(qp1 + 32);
        aq12 = *(const bf16x8*)(qp1 + 64); aq13 = *(const bf16x8*)(qp1 + 96);
    }

    // epilogue operands issued early: overlap with QK
    const float* cbase = c_cache + (size_t)qrow0 * CD + h * HEAD_DIM + dim;
    float cold[2][4];
#pragma unroll
    for (int rt = 0; rt < 2; rt++)
#pragma unroll
        for (int r = 0; r < 4; r++)
            cold[rt][r] = cbase[(size_t)(rt * 16 + quad * 4 + r) * CD];

    // ---- QK^T (A=K, B=Q), prefetch distance 2; dual-write salient P into Pd ----
    float ps0 = 0.f, ps1 = 0.f;
    if (seg_len == MAX_SEG) {
        const size_t krow = (size_t)NUM_KV_HEADS * HEAD_DIM;
        const __bf16* kp = kb + (size_t)(seg_start + wave * 64 + lm) * krow
                              + (size_t)kvh * HEAD_DIM + quad * 8;
        bf16x8 kk[3][4];
        LOADK(0, 0)
        LOADK(1, 1)
#pragma unroll
        for (int tt = 0; tt < 4; tt++) {
            if (tt + 2 < 4) LOADK((tt + 2) % 3, tt + 2)
            const int cur = tt % 3;
            f32x4 a0_ = {0.f,0.f,0.f,0.f}, a1_ = {0.f,0.f,0.f,0.f};
            a0_ = MFMA16(kk[cur][0], aq00, a0_);  a1_ = MFMA16(kk[cur][0], aq10, a1_);
            a0_ = MFMA16(kk[cur][1], aq01, a0_);  a1_ = MFMA16(kk[cur][1], aq11, a1_);
            a0_ = MFMA16(kk[cur][2], aq02, a0_);  a1_ = MFMA16(kk[cur][2], aq12, a1_);
            a0_ = MFMA16(kk[cur][3], aq03, a0_);  a1_ = MFMA16(kk[cur][3], aq13, a1_);
            const int t_ = wave * 4 + tt;
            bf16x4 pk0_, pk1_;
#pragma unroll
            for (int r_ = 0; r_ < 4; r_++) {
                float e0_ = __expf(a0_[r_] * SCALE);
                float e1_ = __expf(a1_[r_] * SCALE);
                ps0 += e0_; ps1 += e1_;
                pk0_[r_] = (__bf16)e0_; pk1_[r_] = (__bf16)e1_;
            }
            *(bf16x4*)&Pb[lm * PB_STRIDE + t_ * 16 + quad * 4] = pk0_;
            *(bf16x4*)&Pb[(16 + lm) * PB_STRIDE + t_ * 16 + quad * 4] = pk1_;
            if (compact) {
                const int4 sal4 = *(const int4*)&rowsal[seg_start + t_ * 16 + quad * 4];
                const int srl[4] = {sal4.x, sal4.y, sal4.z, sal4.w};
#pragma unroll
                for (int r_ = 0; r_ < 4; r_++) {
                    if (srl[r_] >= 0) {
                        const int c_ = srl[r_] - s_lo;
                        Pd[lm * PD_STRIDE + c_]        = pk0_[r_];
                        Pd[(16 + lm) * PD_STRIDE + c_] = pk1_[r_];
                    }
                }
            }
        }
    } else {
        QK_TILE_GEN(0) QK_TILE_GEN(1) QK_TILE_GEN(2) QK_TILE_GEN(3)
    }
#pragma unroll
    for (int m = 16; m <= 32; m <<= 1) {
        ps0 += __shfl_xor(ps0, m, 64);
        ps1 += __shfl_xor(ps1, m, 64);
    }
    if (quad == 0) {
        wred[wave * QT + lm]      = ps0;
        wred[wave * QT + 16 + lm] = ps1;
    }

    // PV pointers; prefetch chunks 0-2 of vnewT (and vdScat on dense path) pre-barrier
    const __bf16* vF = vnewT  + ((size_t)kvh * HEAD_DIM + dim) * Tpad + seg_start + quad * 8;
    const __bf16* vD = vdScat + ((size_t)kvh * HEAD_DIM + dim) * Tpad + seg_start + quad * 8;
    const __bf16* pb0 = &Pb[lm * PB_STRIDE + quad * 8];
    const __bf16* pb1 = &Pb[(16 + lm) * PB_STRIDE + quad * 8];
    bf16x8 fv[4], dv[4];
#pragma unroll
    for (int i = 0; i < 3; i++) {
        fv[i] = *(const bf16x8*)(vF + i * 32);
        if (!compact) dv[i] = *(const bf16x8*)(vD + i * 32);
    }

    __syncthreads();   // barrier1: Pb + Pd + wred complete
    if (tid < QT) {
        float s = 0.f;
#pragma unroll
        for (int w = 0; w < 8; w++) s += wred[w * QT + tid];
        linv[tid] = 1.f / s;
    }

    __builtin_amdgcn_s_setprio(1);
    f32x4 accF0 = {0.f,0.f,0.f,0.f}, accF1 = {0.f,0.f,0.f,0.f};
    f32x4 accD0 = {0.f,0.f,0.f,0.f}, accD1 = {0.f,0.f,0.f,0.f};
    if (compact) {
        // ---- compact PV-delta: <=4 chunks over vdT + Pd ----
        const int ndc = (nss + 31) >> 5;
        const __bf16* vdb = vdT + ((size_t)kvh * HEAD_DIM + dim) * SAL_STRIDE + s_lo + quad * 8;
        const bool al8 = ((s_lo & 7) == 0);
        for (int dc = 0; dc < ndc; dc++) {
            bf16x8 bvD;
            const __bf16* vp = vdb + dc * 32;
            if (al8) bvD = *(const bf16x8*)vp;
            else {
#pragma unroll
                for (int j = 0; j < 8; j++) bvD[j] = vp[j];
            }
            const bf16x8 aD0 = *(const bf16x8*)&Pd[lm * PD_STRIDE + dc * 32 + quad * 8];
            const bf16x8 aD1 = *(const bf16x8*)&Pd[(16 + lm) * PD_STRIDE + dc * 32 + quad * 8];
            accD0 = MFMA16(aD0, bvD, accD0);
            accD1 = MFMA16(aD1, bvD, accD1);
        }
        // ---- PV-full only: 3-deep global prefetch, 1-deep LDS prefetch ----
        if (SEGC == SEGC_MAX) {
            bf16x8 a0c = *(const bf16x8*)(pb0);
            bf16x8 a1c = *(const bf16x8*)(pb1);
#pragma unroll
            for (int cc = 0; cc < SEGC_MAX; cc++) {
                bf16x8 a0n, a1n;
                if (cc + 1 < SEGC_MAX) {
                    a0n = *(const bf16x8*)(pb0 + (cc + 1) * 32);
                    a1n = *(const bf16x8*)(pb1 + (cc + 1) * 32);
                }
                if (cc + 3 < SEGC_MAX)
                    fv[(cc + 3) & 3] = *(const bf16x8*)(vF + (cc + 3) * 32);
                accF0 = MFMA16(a0c, fv[cc & 3], accF0);
                accF1 = MFMA16(a1c, fv[cc & 3], accF1);
                if (cc + 1 < SEGC_MAX) { a0c = a0n; a1c = a1n; }
            }
        } else {
            for (int cc = 0; cc < SEGC; cc++) {
                const bf16x8 bF_ = *(const bf16x8*)(vF + cc * 32);
                accF0 = MFMA16(*(const bf16x8*)(pb0 + cc * 32), bF_, accF0);
                accF1 = MFMA16(*(const bf16x8*)(pb1 + cc * 32), bF_, accF1);
            }
        }
    } else {
        // ---- dense fallback: fused PV over vnewT + vdScat (R7 path, verbatim) ----
        if (SEGC == SEGC_MAX) {
            bf16x8 a0c = *(const bf16x8*)(pb0);
            bf16x8 a1c = *(const bf16x8*)(pb1);
#pragma unroll
            for (int cc = 0; cc < SEGC_MAX; cc++) {
                bf16x8 a0n, a1n;
                if (cc + 1 < SEGC_MAX) {
                    a0n = *(const bf16x8*)(pb0 + (cc + 1) * 32);
                    a1n = *(const bf16x8*)(pb1 + (cc + 1) * 32);
                }
                if (cc + 3 < SEGC_MAX) {
                    fv[(cc + 3) & 3] = *(const bf16x8*)(vF + (cc + 3) * 32);
                    dv[(cc + 3) & 3] = *(const bf16x8*)(vD + (cc + 3) * 32);
                }
                const int cur = cc & 3;
                accF0 = MFMA16(a0c, fv[cur], accF0);
                accF1 = MFMA16(a1c, fv[cur], accF1);
                accD0 = MFMA16(a0c, dv[cur], accD0);
                accD1 = MFMA16(a1c, dv[cur], accD1);
                if (cc + 1 < SEGC_MAX) { a0c = a0n; a1c = a1n; }
            }
        } else {
            for (int cc = 0; cc < SEGC; cc++) {
                const bf16x8 bF_ = *(const bf16x8*)(vF + cc * 32);
                const bf16x8 bD_ = *(const bf16x8*)(vD + cc * 32);
                const bf16x8 a0_ = *(const bf16x8*)(pb0 + cc * 32);
                const bf16x8 a1_ = *(const bf16x8*)(pb1 + cc * 32);
                accF0 = MFMA16(a0_, bF_, accF0);
                accF1 = MFMA16(a1_, bF_, accF1);
                accD0 = MFMA16(a0_, bD_, accD0);
                accD1 = MFMA16(a1_, bD_, accD1);
            }
        }
    }
    __builtin_amdgcn_s_setprio(0);
    __syncthreads();   // barrier2: linv visible

    // ---- epilogue: outputs + cosine partials, single pass over all 32 rows ----
    float* obase = out_c + (size_t)qrow0 * CD + h * HEAD_DIM + dim;
#pragma unroll
    for (int rt = 0; rt < 2; rt++) {
#pragma unroll
        for (int r = 0; r < 4; r++) {
            const int row = rt * 16 + quad * 4 + r;
            const float c_old = cold[rt][r];
            const float li = linv[row];
            const float aF = (rt == 0) ? accF0[r] : accF1[r];
            const float aD = (rt == 0) ? accD0[r] : accD1[r];
            const float o = (salrow[row] >= 0) ? aF * li : c_old + aD * li;
            obase[(size_t)row * CD] = o;
            float xn = o * c_old, xc = c_old * c_old, xd = o * o;
            red16(xn, xc, xd);
            if (lm == 0) {
                cp[(wave * 3 + 0) * QT + row] = xn;
                cp[(wave * 3 + 1) * QT + row] = xc;
                cp[(wave * 3 + 2) * QT + row] = xd;
            }
        }
    }
    __syncthreads();   // barrier3: cp complete
    for (int ii = tid; ii < 3 * QT; ii += BLK) {
        int c = ii >> 5, row = ii & 31;
        float s = 0.f;
#pragma unroll
        for (int w = 0; w < 8; w++) s += cp[(w * 3 + c) * QT + row];
        // layout [row][3][32] for coalesced finalize
        cospart[((size_t)(qrow0 + row) * 3 + c) * NUM_HEADS + h] = s;
    }
}

// ---------------- cos finalize: one row per wave, coalesced ----------------
__global__ void cos_finalize(const float* __restrict__ cospart, float* __restrict__ out_cos, int T) {
    const int lane = threadIdx.x & 63;
    const int row  = blockIdx.x * 4 + (threadIdx.x >> 6);
    if (row >= T) return;
    const float* p = cospart + (size_t)row * (NUM_HEADS * 3);
    float a = p[lane];                               // lanes 0-31: num, lanes 32-63: den_c
    float b = (lane < 32) ? p[64 + lane] : 0.f;      // den_n
#pragma unroll
    for (int m = 1; m <= 16; m <<= 1) {
        a += __shfl_xor(a, m, 64);
        b += __shfl_xor(b, m, 64);
    }
    float den_c = __shfl(a, 32, 64);
    if (lane == 0) out_cos[row] = a / (sqrtf(den_c) * sqrtf(b) + EPS);
}

extern "C" void kernel_launch(void* const* d_in, const int* in_sizes, int n_in,
                              void* d_out, int out_size, void* d_ws, size_t ws_size,
                              hipStream_t stream) {
    const float* q       = (const float*)d_in[0];
    const float* k       = (const float*)d_in[1];
    const float* v       = (const float*)d_in[2];
    const float* v_cache = (const float*)d_in[3];
    const float* c_cache = (const float*)d_in[4];
    const int*   idx     = (const int*)d_in[5];
    const int*   cu      = (const int*)d_in[6];

    const int T     = in_sizes[0] / CD;
    const int n_sal = in_sizes[5];
    const int n_seq = in_sizes[6] - 1;
    const int Tpad  = T + 32;
    const int NT    = T / QT;
    const int use_compact = (n_sal <= SAL_PAD) ? 1 : 0;

    float* out_c   = (float*)d_out;
    float* out_cos = out_c + (size_t)T * CD;

    char* wsp = (char*)d_ws;
    size_t off = 0;
    __bf16* kb = (__bf16*)(wsp + off);
    off += (((size_t)T * NUM_KV_HEADS * HEAD_DIM * 2) + 255) & ~(size_t)255;
    __bf16* qb = (__bf16*)(wsp + off);
    off += (((size_t)T * NUM_HEADS * HEAD_DIM * 2) + 255) & ~(size_t)255;
    __bf16* vnewT = (__bf16*)(wsp + off);
    off += (((size_t)NUM_KV_HEADS * HEAD_DIM * Tpad * 2) + 255) & ~(size_t)255;
    __bf16* vdScat = (__bf16*)(wsp + off);
    off += (((size_t)NUM_KV_HEADS * HEAD_DIM * Tpad * 2) + 255) & ~(size_t)255;
    __bf16* vdT = (__bf16*)(wsp + off);
    off += (((size_t)NUM_KV_HEADS * HEAD_DIM * SAL_STRIDE * 2) + 255) & ~(size_t)255;
    float* cospart = (float*)(wsp + off);
    off += ((size_t)T * NUM_HEADS * 3 * 4 + 255) & ~(size_t)255;
    int* tinfo = (int*)(wsp + off);
    off += ((size_t)NT * 4 * 4 + 255) & ~(size_t)255;
    int* rowsal = (int*)(wsp + off);
    off += ((size_t)T * 4 + 255) & ~(size_t)255;
    (void)ws_size;

    const int n8_tot  = T * HEAD_DIM * (NUM_KV_HEADS + NUM_HEADS) / 8;
    const int nb_conv = (n8_tot + 255) / 256;
    const int nb_vt   = (Tpad + 63) / 64;
    const int nb_vd   = use_compact ? (SAL_STRIDE / 64) : 0;
    const int nb_tot  = nb_conv + nb_vt * NUM_KV_HEADS + nb_vd * NUM_KV_HEADS + 1;

    prep<<<nb_tot, 256, 0, stream>>>(k, q, v, v_cache, idx, cu, kb, qb, vnewT,
                                     vdScat, vdT, tinfo, rowsal, T, Tpad, n_sal,
                                     n_seq, nb_conv, nb_vt, nb_vd, use_compact);

    // 1-D grid: bid&7 = kvh (XCD pin), then head-within-group, then q-tile
    attn_mfma<<<NT * NUM_HEADS, BLK, 0, stream>>>(qb, kb, vnewT, vdScat, vdT, c_cache,
                                                  tinfo, rowsal, out_c, cospart,
                                                  Tpad, use_compact);

    cos_finalize<<<(T + 3) / 4, 256, 0, stream>>>(cospart, out_cos, T);
}